// Round 12
// baseline (417.843 us; speedup 1.0000x reference)
//
#include <hip/hip_runtime.h>
#include <math.h>

// Problem constants (B=16, N=M=2048, eps=0.05, 10 sinkhorn iters)
#define NPTS    2048
#define NBATCH  16
#define THREADS 256
#define ROWS_PER_BLOCK   32
#define ROWS_PER_WAVE    8
#define IPAIRS  1024            // i as pairs of ADJACENT sorted points (2m, 2m+1)
#define NCHUNK  16              // 16 chunks x 128 sorted points

typedef __attribute__((ext_vector_type(2))) float f2;

static constexpr float KEPS_L  = 28.853900817779268f;   // log2(e)/eps
static constexpr float LOGMU_L = -11.0f;                 // -log2(2048), exact
static constexpr float EPS_LN2 = 0.03465735902799727f;   // eps*ln(2)
static constexpr float INV_K2  = 1.2011331562368226e-3f; // 1/KEPS_L^2
static constexpr float GUARD   = 24.0f;                  // prune guard (log2 units)

__device__ inline unsigned spread10(unsigned v) {
  v = (v | (v << 16)) & 0x030000FFu;
  v = (v | (v << 8))  & 0x0300F00Fu;
  v = (v | (v << 4))  & 0x030C30C3u;
  v = (v | (v << 2))  & 0x09249249u;
  return v;
}

// Deterministic Morton bitonic sort of each cloud (one block per batch x cloud),
// writes K-scaled sorted float4 {Kx,Ky,Kz,|Kp|^2} and per-chunk bboxes (scaled).
// Bitonic is a fixed comparator network -> output depends only on input: the
// graph-replay determinism contract holds. All downstream consumers (duals,
// chamfer, sums) are permutation-invariant.
__global__ __launch_bounds__(1024)
void sort_pack(const float* __restrict__ inA, const float* __restrict__ inB,
               float4* __restrict__ p4A, float4* __restrict__ p4B,
               float* __restrict__ bbA, float* __restrict__ bbB) {
  __shared__ unsigned skey[NPTS];
  __shared__ unsigned sidx[NPTS];
  const int b  = blockIdx.x >> 1;
  const int cb = blockIdx.x & 1;
  const float* __restrict__ src = (cb ? inB : inA) + (size_t)b * NPTS * 3;
  float4* __restrict__ dst = (cb ? p4B : p4A) + (size_t)b * NPTS;
  float*  __restrict__ bbo = (cb ? bbB : bbA) + (size_t)b * NCHUNK * 8;
  const int t = threadIdx.x;

  for (int k = t; k < NPTS; k += 1024) {
    float x = src[3*k], y = src[3*k+1], z = src[3*k+2];
    unsigned xi = (unsigned)(int)fminf(fmaxf((x + 5.12f) * 100.0f, 0.f), 1023.f);
    unsigned yi = (unsigned)(int)fminf(fmaxf((y + 5.12f) * 100.0f, 0.f), 1023.f);
    unsigned zi = (unsigned)(int)fminf(fmaxf((z + 5.12f) * 100.0f, 0.f), 1023.f);
    skey[k] = (spread10(xi) << 2) | (spread10(yi) << 1) | spread10(zi);
    sidx[k] = k;
  }
  __syncthreads();
  for (int kk = 2; kk <= NPTS; kk <<= 1) {
    for (int j = kk >> 1; j > 0; j >>= 1) {
      for (int t2 = t; t2 < NPTS; t2 += 1024) {
        int p = t2 ^ j;
        if (p > t2) {
          bool up = (t2 & kk) == 0;
          unsigned ka = skey[t2], kb = skey[p];
          if (up ? (ka > kb) : (ka < kb)) {
            skey[t2] = kb; skey[p] = ka;
            unsigned ia = sidx[t2]; sidx[t2] = sidx[p]; sidx[p] = ia;
          }
        }
      }
      __syncthreads();
    }
  }
  // K-scaled packed write (thread t owns sorted points 2t, 2t+1)
  const int i0 = sidx[2*t], i1 = sidx[2*t+1];
  float x0 = KEPS_L*src[3*i0], y0 = KEPS_L*src[3*i0+1], z0 = KEPS_L*src[3*i0+2];
  float x1 = KEPS_L*src[3*i1], y1 = KEPS_L*src[3*i1+1], z1 = KEPS_L*src[3*i1+2];
  float w0 = fmaf(x0, x0, fmaf(y0, y0, z0*z0));
  float w1 = fmaf(x1, x1, fmaf(y1, y1, z1*z1));
  dst[2*t]   = make_float4(x0, y0, z0, w0);
  dst[2*t+1] = make_float4(x1, y1, z1, w1);
  // per-chunk bbox: wave id (t>>6) == chunk id; reduce 6 values over 64 lanes
  float mnx = fminf(x0,x1), mny = fminf(y0,y1), mnz = fminf(z0,z1);
  float mxx = fmaxf(x0,x1), mxy = fmaxf(y0,y1), mxz = fmaxf(z0,z1);
#pragma unroll
  for (int off = 32; off; off >>= 1) {
    mnx = fminf(mnx, __shfl_xor(mnx, off));
    mny = fminf(mny, __shfl_xor(mny, off));
    mnz = fminf(mnz, __shfl_xor(mnz, off));
    mxx = fmaxf(mxx, __shfl_xor(mxx, off));
    mxy = fmaxf(mxy, __shfl_xor(mxy, off));
    mxz = fmaxf(mxz, __shfl_xor(mxz, off));
  }
  if ((t & 63) == 0) {
    const int c = t >> 6;
    bbo[c*8+0] = mnx; bbo[c*8+1] = mny; bbo[c*8+2] = mnz;
    bbo[c*8+3] = mxx; bbo[c*8+4] = mxy; bbo[c*8+5] = mxz;
  }
}

// One half-iteration of log-domain Sinkhorn (exp2-domain, per-batch shift A).
// SoA-f2 LDS over ADJACENT sorted pairs (2m,2m+1); q-splats hoisted.
// CHAMFER passes (1,2): unpruned; also write per-row min scaled-d2 (rmOut).
// PRUNE passes (3..20): per-wave 16-chunk skip mask — chunk droppable for a
// row iff bboxdist > sqrt(rmin2)+W+GUARD (W = dual spread, exact per pass);
// total dropped mass <= S*2^-14. Rows are 8 consecutive SORTED points ->
// spatially tight -> high joint skip rate. Mask is wave-uniform (ballot ->
// scalar branch), zero divergence.
template<bool INIT, bool CHAMFER, bool PRUNE>
__global__ __launch_bounds__(THREADS)
void lse_pass(const float4* __restrict__ pR, const float4* __restrict__ pQ,
              const float* __restrict__ dualR, float* __restrict__ dualQ,
              float* __restrict__ chamPart, float* __restrict__ rmOut,
              const float* __restrict__ rmIn, const float* __restrict__ bbR) {
  __shared__ f2 sxx[IPAIRS];
  __shared__ f2 syy[IPAIRS];
  __shared__ f2 szz[IPAIRS];
  __shared__ f2 sww[IPAIRS];   // {-0.5|Kp|^2}
  __shared__ f2 swt[IPAIRS];   // {2^(a_i - A)}
  // 40960 B exactly -> 4 blocks/CU; sxx doubles as reduce scratch.

  const int b    = blockIdx.x >> 6;
  const int blk  = blockIdx.x & 63;
  const int tid  = threadIdx.x;
  const int lane = tid & 63;
  const int wave = tid >> 6;

  const float4* __restrict__ px = pR + b * NPTS;
  float A, W = 0.f;

  if constexpr (INIT) {
#pragma unroll
    for (int u = 0; u < 4; ++u) {
      int m = tid + u * THREADS;
      float4 a4 = px[2*m], b4 = px[2*m+1];
      sxx[m] = (f2){a4.x, b4.x};
      syy[m] = (f2){a4.y, b4.y};
      szz[m] = (f2){a4.z, b4.z};
      sww[m] = (f2){-0.5f * a4.w, -0.5f * b4.w};
      swt[m] = (f2){1.f, 1.f};
    }
    A = LOGMU_L;
    __syncthreads();
  } else {
    const f2* __restrict__ fb2 = (const f2*)(dualR + b * NPTS);
    const f2 kK  = (f2){KEPS_L, KEPS_L};
    const f2 kLM = (f2){LOGMU_L, LOGMU_L};
    f2 av2[4];
    float lm = -3.4e38f, lmn = 3.4e38f;
#pragma unroll
    for (int u = 0; u < 4; ++u) {
      int m = tid + u * THREADS;
      f2 a2 = __builtin_elementwise_fma(fb2[m], kK, kLM);
      av2[u] = a2;
      lm  = fmaxf(lm,  fmaxf(a2.x, a2.y));
      lmn = fminf(lmn, fminf(a2.x, a2.y));
    }
#pragma unroll
    for (int off = 32; off; off >>= 1) {
      lm  = fmaxf(lm,  __shfl_xor(lm,  off));
      lmn = fminf(lmn, __shfl_xor(lmn, off));
    }
    float* scratch = (float*)sxx;          // sxx not yet staged
    if (lane == 0) { scratch[wave] = lm; scratch[8 + wave] = lmn; }
    __syncthreads();
    A = fmaxf(fmaxf(scratch[0], scratch[1]), fmaxf(scratch[2], scratch[3]));
    float Amin = fminf(fminf(scratch[8], scratch[9]), fminf(scratch[10], scratch[11]));
    W = A - Amin;
    __syncthreads();
#pragma unroll
    for (int u = 0; u < 4; ++u) {
      int m = tid + u * THREADS;
      float4 a4 = px[2*m], b4 = px[2*m+1];
      sxx[m] = (f2){a4.x, b4.x};
      syy[m] = (f2){a4.y, b4.y};
      szz[m] = (f2){a4.z, b4.z};
      sww[m] = (f2){-0.5f * a4.w, -0.5f * b4.w};
      swt[m] = (f2){__builtin_amdgcn_exp2f(av2[u].x - A),
                    __builtin_amdgcn_exp2f(av2[u].y - A)};
    }
    __syncthreads();
  }

  const float4* __restrict__ qa = pQ + b * NPTS;
  float* __restrict__ gout = dualQ + b * NPTS;
  const int j0 = blk * ROWS_PER_BLOCK + wave * ROWS_PER_WAVE;

  f2 qxx[8], qyy[8], qzz[8], qww[8], s2[8], m2[8];
#pragma unroll
  for (int r = 0; r < ROWS_PER_WAVE; ++r) {
    float4 q = qa[j0 + r];
    qxx[r] = (f2){q.x, q.x};
    qyy[r] = (f2){q.y, q.y};
    qzz[r] = (f2){q.z, q.z};
    qww[r] = (f2){q.w, q.w};
    s2[r] = (f2){0.f, 0.f};
    if constexpr (CHAMFER) m2[r] = (f2){3.4e38f, 3.4e38f};
  }

  // --- chunk skip mask (wave-uniform) ---
  unsigned long long bal = 0;
  if constexpr (PRUNE) {
    const int c = lane >> 2, rp = lane & 3;     // chunk, row-pair
    const float* bbc = bbR + ((size_t)b * NCHUNK + c) * 8;
    const float bmx = bbc[0], bmy = bbc[1], bmz = bbc[2];
    const float bXx = bbc[3], bXy = bbc[4], bXz = bbc[5];
    const float* rq = rmIn + b * NPTS + j0;
    float4 qA = qa[j0 + 2*rp];
    float4 qB = qa[j0 + 2*rp + 1];
    float ca = __builtin_amdgcn_sqrtf(rq[2*rp])     + W + GUARD;
    float cb = __builtin_amdgcn_sqrtf(rq[2*rp + 1]) + W + GUARD;
    float dxa = fmaxf(fmaxf(bmx - qA.x, qA.x - bXx), 0.f);
    float dya = fmaxf(fmaxf(bmy - qA.y, qA.y - bXy), 0.f);
    float dza = fmaxf(fmaxf(bmz - qA.z, qA.z - bXz), 0.f);
    float da2 = fmaf(dxa, dxa, fmaf(dya, dya, dza*dza));
    float dxb = fmaxf(fmaxf(bmx - qB.x, qB.x - bXx), 0.f);
    float dyb = fmaxf(fmaxf(bmy - qB.y, qB.y - bXy), 0.f);
    float dzb = fmaxf(fmaxf(bmz - qB.z, qB.z - bXz), 0.f);
    float db2 = fmaf(dxb, dxb, fmaf(dyb, dyb, dzb*dzb));
    int ski = (da2 > ca * ca) && (db2 > cb * cb);
    ski &= __shfl_xor(ski, 1);
    ski &= __shfl_xor(ski, 2);
    bal = __ballot(ski != 0);                  // bit 4c set iff chunk c skippable
  }

  const f2 kM2 = (f2){-2.f, -2.f};

  for (int it = 0; it < IPAIRS / 64; ++it) {
    if constexpr (PRUNE) { if ((bal >> (4 * it)) & 1) continue; }
    const int k = it * 64 + lane;
    const f2 pxx = sxx[k];
    const f2 pyy = syy[k];
    const f2 pzz = szz[k];
    const f2 pww = sww[k];
    const f2 wt  = swt[k];
#pragma unroll
    for (int r = 0; r < ROWS_PER_WAVE; ++r) {
      f2 t  = __builtin_elementwise_fma(pxx, qxx[r],
              __builtin_elementwise_fma(pyy, qyy[r],
              __builtin_elementwise_fma(pzz, qzz[r], pww)));
      f2 d2 = __builtin_elementwise_fma(kM2, t, qww[r]);   // = K^2*dist^2 > 0
      if constexpr (CHAMFER) m2[r] = __builtin_elementwise_min(m2[r], d2);
      f2 e;
      e.x = __builtin_amdgcn_exp2f(-__builtin_amdgcn_sqrtf(d2.x));
      e.y = __builtin_amdgcn_exp2f(-__builtin_amdgcn_sqrtf(d2.y));
      s2[r] = __builtin_elementwise_fma(e, wt, s2[r]);
    }
  }

  float s[ROWS_PER_WAVE], m[ROWS_PER_WAVE];
#pragma unroll
  for (int r = 0; r < ROWS_PER_WAVE; ++r) {
    s[r] = s2[r].x + s2[r].y;
    if constexpr (CHAMFER) m[r] = fminf(m2[r].x, m2[r].y);
  }
#pragma unroll
  for (int off = 32; off; off >>= 1) {
#pragma unroll
    for (int r = 0; r < ROWS_PER_WAVE; ++r) {
      s[r] += __shfl_xor(s[r], off);
      if constexpr (CHAMFER) m[r] = fminf(m[r], __shfl_xor(m[r], off));
    }
  }

  if (lane == 0) {
#pragma unroll
    for (int r = 0; r < ROWS_PER_WAVE; ++r) {
      gout[j0 + r] = -EPS_LN2 * (A + __builtin_amdgcn_logf(fmaxf(s[r], 1e-37f)));
      if constexpr (CHAMFER) rmOut[b * NPTS + j0 + r] = m[r];   // scaled min d2
    }
  }

  if constexpr (CHAMFER) {
    float chamAcc = 0.f;
#pragma unroll
    for (int r = 0; r < ROWS_PER_WAVE; ++r) chamAcc += m[r];
    chamAcc *= INV_K2;
    __syncthreads();
    float* scratch = (float*)sxx;
    if (lane == 0) scratch[wave] = chamAcc;
    __syncthreads();
    if (tid == 0)
      chamPart[blockIdx.x] = (scratch[0] + scratch[1]) + (scratch[2] + scratch[3]);
  }
}

// Stage 1: 66 blocks x 256 threads (66*256*4 = 67584 floats = f+g+cham).
__global__ void final1(const float4* __restrict__ base, float* __restrict__ part) {
  __shared__ float red[4];
  const int idx = blockIdx.x * 256 + threadIdx.x;
  float4 v = base[idx];
  float acc = (v.x + v.y) + (v.z + v.w);
#pragma unroll
  for (int off = 32; off; off >>= 1) acc += __shfl_xor(acc, off);
  const int lane = threadIdx.x & 63, wave = threadIdx.x >> 6;
  if (lane == 0) red[wave] = acc;
  __syncthreads();
  if (threadIdx.x == 0) part[blockIdx.x] = (red[0] + red[1]) + (red[2] + red[3]);
}

__global__ void final2(const float* __restrict__ part, float* __restrict__ out) {
  const int lane = threadIdx.x;
  float acc = part[lane];
  if (lane < 2) acc += part[lane + 64];
#pragma unroll
  for (int off = 32; off; off >>= 1) acc += __shfl_xor(acc, off);
  if (lane == 0) out[0] = acc;
}

extern "C" void kernel_launch(void* const* d_in, const int* in_sizes, int n_in,
                              void* d_out, int out_size, void* d_ws, size_t ws_size,
                              hipStream_t stream) {
  const float* outPts = (const float*)d_in[0];
  const float* tgtPts = (const float*)d_in[1];
  float* out = (float*)d_out;

  char* ws = (char*)d_ws;
  float4* p4A = (float4*)ws;                                   // 512 KB
  float4* p4B = (float4*)(ws + (size_t)NBATCH * NPTS * 16);    // 512 KB
  float*  f    = (float*)(ws + (size_t)2 * NBATCH * NPTS * 16);// 32768
  float*  g    = f + NBATCH * NPTS;                            // 32768
  float*  cham = g + NBATCH * NPTS;                            // 2048
  float*  part = cham + 2048;                                  // 66 (+pad)
  float*  rmA  = part + 128;                                   // 32768
  float*  rmB  = rmA + NBATCH * NPTS;                          // 32768
  float*  bbA  = rmB + NBATCH * NPTS;                          // 2048
  float*  bbB  = bbA + NBATCH * NCHUNK * 8;                    // 2048
  // total ws use ~1.6 MB (ws is 256 MB)

  sort_pack<<<dim3(2 * NBATCH), dim3(1024), 0, stream>>>(outPts, tgtPts,
                                                         p4A, p4B, bbA, bbB);

  const dim3 grid(NBATCH * 64);   // 1024 blocks
  const dim3 blk(THREADS);

  // pass 1/2: unpruned, chamfer + rmin bootstrap
  lse_pass<true,  true,  false><<<grid, blk, 0, stream>>>(p4A, p4B, nullptr, g,
      cham, rmB, nullptr, nullptr);
  lse_pass<false, true,  false><<<grid, blk, 0, stream>>>(p4B, p4A, g, f,
      cham + 1024, rmA, nullptr, nullptr);
  // passes 3..20: pruned
  for (int t = 1; t < 10; ++t) {
    lse_pass<false, false, true><<<grid, blk, 0, stream>>>(p4A, p4B, f, g,
        nullptr, nullptr, rmB, bbA);
    lse_pass<false, false, true><<<grid, blk, 0, stream>>>(p4B, p4A, g, f,
        nullptr, nullptr, rmA, bbB);
  }

  final1<<<dim3(66), dim3(256), 0, stream>>>((const float4*)f, part);
  final2<<<dim3(1), dim3(64), 0, stream>>>(part, out);
}

// Round 13
// 380.624 us; speedup vs baseline: 1.0978x; 1.0978x over previous
//
#include <hip/hip_runtime.h>
#include <math.h>

// Problem constants (B=16, N=M=2048, eps=0.05, 10 sinkhorn iters)
#define NPTS    2048
#define NBATCH  16
#define THREADS 256
#define BLOCKS_PER_BATCH 64     // 1024 blocks = 4/CU x 256 CU exactly
#define ROWS_PER_BLOCK   32
#define ROWS_PER_WAVE    8
#define IPAIRS  1024            // i handled as pairs (k, k+1024)

typedef __attribute__((ext_vector_type(2))) float f2;

static constexpr float KEPS_L  = 28.853900817779268f;   // log2(e)/eps
static constexpr float LOGMU_L = -11.0f;                 // -log2(2048), exact
static constexpr float EPS_LN2 = 0.03465735902799727f;   // eps*ln(2)
static constexpr float INV_K2  = 1.2011331562368226e-3f; // 1/KEPS_L^2
// exp2-chord centering: bitcast approx has ratio h(m)=(1-m/2)*2^m, mean 1.0407.
// Fold 1/1.0407 into the staged weights: log2(0.96089) = -0.057549
static constexpr float CHORD_C  = 0.9608858f;
static constexpr float CHORD_LC = -0.05754863f;

// Pack both point clouds as K-scaled float4 {Kx,Ky,Kz,|Kp|^2}.
__global__ void pack_pts(const float* __restrict__ a, const float* __restrict__ b,
                         float4* __restrict__ pa, float4* __restrict__ pb) {
  int idx = blockIdx.x * blockDim.x + threadIdx.x;
  if (idx < NBATCH * NPTS) {
    float x = KEPS_L * a[3*idx], y = KEPS_L * a[3*idx+1], z = KEPS_L * a[3*idx+2];
    pa[idx] = make_float4(x, y, z, fmaf(x, x, fmaf(y, y, z*z)));
    float u = KEPS_L * b[3*idx], v = KEPS_L * b[3*idx+1], w = KEPS_L * b[3*idx+2];
    pb[idx] = make_float4(u, v, w, fmaf(u, u, fmaf(v, v, w*w)));
  }
}

// One half-iteration of log-domain Sinkhorn (exp2-domain, per-batch shift A).
// Model (fit r4-r12): SIMD issue with wave64 VALU ~2 cyc, trans ~16 cyc;
// trans was ~80% of the budget. This version halves trans count: keep HW
// v_sqrt (needed in-chain), replace v_exp with the IEEE bit-trick
//   2^(-r) ~= bitcast_f32( (int)((127 - r) * 2^23) )     (chord approx)
// clamped at 0 for r>127 (term underflows -> exact 0). The chord's mean
// ratio 1.0407 is folded into the staged weights (CHORD_LC), leaving +-4%
// zero-mean per-term noise -> f/g error O(0.003)/entry, total << threshold.
// Chamfer path (exact d2) untouched. SoA-f2 LDS over i-pairs (k, k+1024),
// q-splats hoisted; no min-occupancy launch_bounds (r10: forcing 4 w/SIMD
// at 64 VGPR caused 250 MB/dispatch scratch spills).
template<bool INIT, bool CHAMFER>
__global__ __launch_bounds__(THREADS)
void lse_pass(const float4* __restrict__ pR, const float4* __restrict__ pQ,
              const float* __restrict__ dualR, float* __restrict__ dualQ,
              float* __restrict__ chamPart) {
  __shared__ f2 sxx[IPAIRS];
  __shared__ f2 syy[IPAIRS];
  __shared__ f2 szz[IPAIRS];
  __shared__ f2 sww[IPAIRS];   // {-0.5|Kp|^2 lo, hi}
  __shared__ f2 swt[IPAIRS];   // {c*2^(a_i - A) lo, hi}
  // total 40960 B exactly -> 4 blocks/CU; sxx doubles as reduce scratch.

  const int b    = blockIdx.x >> 6;        // batch
  const int blk  = blockIdx.x & 63;        // block within batch
  const int tid  = threadIdx.x;
  const int lane = tid & 63;
  const int wave = tid >> 6;

  const float4* __restrict__ px = pR + b * NPTS;
  float A;

  if constexpr (INIT) {
    // f == 0: a_i = LOGMU_L for all i -> A = LOGMU_L, w_i = CHORD_C
#pragma unroll
    for (int u = 0; u < 4; ++u) {
      int k = tid + u * THREADS;
      float4 a4 = px[k];
      float4 b4 = px[k + IPAIRS];
      sxx[k] = (f2){a4.x, b4.x};
      syy[k] = (f2){a4.y, b4.y};
      szz[k] = (f2){a4.z, b4.z};
      sww[k] = (f2){-0.5f * a4.w, -0.5f * b4.w};
      swt[k] = (f2){CHORD_C, CHORD_C};
    }
    A = LOGMU_L;
    __syncthreads();
  } else {
    const float* __restrict__ fb = dualR + b * NPTS;
    float av[8];
    float lm = -3.4e38f;
#pragma unroll
    for (int u = 0; u < 8; ++u) {
      int k = tid + u * THREADS;
      float a = fmaf(fb[k], KEPS_L, LOGMU_L);
      av[u] = a;
      lm = fmaxf(lm, a);
    }
#pragma unroll
    for (int off = 32; off; off >>= 1) lm = fmaxf(lm, __shfl_xor(lm, off));
    float* scratch = (float*)sxx;          // sxx not yet staged -> usable
    if (lane == 0) scratch[wave] = lm;
    __syncthreads();
    A = fmaxf(fmaxf(scratch[0], scratch[1]), fmaxf(scratch[2], scratch[3]));
    __syncthreads();                       // done reading scratch before staging
#pragma unroll
    for (int u = 0; u < 4; ++u) {
      int k = tid + u * THREADS;           // 0..1023; partner k+1024 -> av[u+4]
      float4 a4 = px[k];
      float4 b4 = px[k + IPAIRS];
      sxx[k] = (f2){a4.x, b4.x};
      syy[k] = (f2){a4.y, b4.y};
      szz[k] = (f2){a4.z, b4.z};
      sww[k] = (f2){-0.5f * a4.w, -0.5f * b4.w};
      swt[k] = (f2){__builtin_amdgcn_exp2f(av[u] - A + CHORD_LC),
                    __builtin_amdgcn_exp2f(av[u + 4] - A + CHORD_LC)};
    }
    __syncthreads();
  }

  const float4* __restrict__ qa = pQ + b * NPTS;
  float* __restrict__ gout = dualQ + b * NPTS;
  const int j0 = blk * ROWS_PER_BLOCK + wave * ROWS_PER_WAVE;

  // Q-side splats hoisted out of the loop (loop-invariant f2 constants)
  f2 qxx[8], qyy[8], qzz[8], qww[8], s2[8], m2[8];
#pragma unroll
  for (int r = 0; r < ROWS_PER_WAVE; ++r) {
    float4 q = qa[j0 + r];
    qxx[r] = (f2){q.x, q.x};
    qyy[r] = (f2){q.y, q.y};
    qzz[r] = (f2){q.z, q.z};
    qww[r] = (f2){q.w, q.w};
    s2[r] = (f2){0.f, 0.f};
    if constexpr (CHAMFER) m2[r] = (f2){3.4e38f, 3.4e38f};
  }

  const f2 kM2 = (f2){-2.f, -2.f};
  const f2 kB  = (f2){1065353216.f, 1065353216.f};   // 127 * 2^23
  const f2 kS  = (f2){-8388608.f, -8388608.f};       // -2^23
  const f2 kZ  = (f2){0.f, 0.f};

#pragma unroll 2
  for (int it = 0; it < IPAIRS / 64; ++it) {
    const int k = it * 64 + lane;
    const f2 pxx = sxx[k];
    const f2 pyy = syy[k];
    const f2 pzz = szz[k];
    const f2 pww = sww[k];
    const f2 wt  = swt[k];
#pragma unroll
    for (int r = 0; r < ROWS_PER_WAVE; ++r) {
      f2 t  = __builtin_elementwise_fma(pxx, qxx[r],
              __builtin_elementwise_fma(pyy, qyy[r],
              __builtin_elementwise_fma(pzz, qzz[r], pww)));
      f2 d2 = __builtin_elementwise_fma(kM2, t, qww[r]);   // = K^2*dist^2 > 0
      if constexpr (CHAMFER) m2[r] = __builtin_elementwise_min(m2[r], d2);
      f2 rr;
      rr.x = __builtin_amdgcn_sqrtf(d2.x);                 // r = K*dist
      rr.y = __builtin_amdgcn_sqrtf(d2.y);
      // fast exp2: e ~= bitcast((int)((127 - r)*2^23)), clamped at 0
      f2 tt = __builtin_elementwise_fma(rr, kS, kB);
      tt = __builtin_elementwise_max(tt, kZ);
      f2 e;
      e.x = __int_as_float((int)tt.x);
      e.y = __int_as_float((int)tt.y);
      s2[r] = __builtin_elementwise_fma(e, wt, s2[r]);
    }
  }

  float s[ROWS_PER_WAVE], m[ROWS_PER_WAVE];
#pragma unroll
  for (int r = 0; r < ROWS_PER_WAVE; ++r) {
    s[r] = s2[r].x + s2[r].y;
    if constexpr (CHAMFER) m[r] = fminf(m2[r].x, m2[r].y);
  }

  // full-wave xor reductions (all lanes end with the result)
#pragma unroll
  for (int off = 32; off; off >>= 1) {
#pragma unroll
    for (int r = 0; r < ROWS_PER_WAVE; ++r) {
      s[r] += __shfl_xor(s[r], off);
      if constexpr (CHAMFER) m[r] = fminf(m[r], __shfl_xor(m[r], off));
    }
  }

  if (lane == 0) {
#pragma unroll
    for (int r = 0; r < ROWS_PER_WAVE; ++r)
      gout[j0 + r] = -EPS_LN2 * (A + __builtin_amdgcn_logf(fmaxf(s[r], 1e-37f)));
  }

  if constexpr (CHAMFER) {
    float chamAcc = 0.f;
#pragma unroll
    for (int r = 0; r < ROWS_PER_WAVE; ++r) chamAcc += m[r];
    chamAcc *= INV_K2;                      // back to unscaled d2
    __syncthreads();                        // everyone done with LDS arrays
    float* scratch = (float*)sxx;
    if (lane == 0) scratch[wave] = chamAcc;
    __syncthreads();
    if (tid == 0)
      chamPart[blockIdx.x] = (scratch[0] + scratch[1]) + (scratch[2] + scratch[3]);
  }
}

// Stage 1: 66 blocks x 256 threads, one float4 per thread (66*256*4 = 67584
// floats = f(32768) + g(32768) + cham(2048), contiguous). Deterministic.
__global__ void final1(const float4* __restrict__ base, float* __restrict__ part) {
  __shared__ float red[4];
  const int idx = blockIdx.x * 256 + threadIdx.x;
  float4 v = base[idx];
  float acc = (v.x + v.y) + (v.z + v.w);
#pragma unroll
  for (int off = 32; off; off >>= 1) acc += __shfl_xor(acc, off);
  const int lane = threadIdx.x & 63, wave = threadIdx.x >> 6;
  if (lane == 0) red[wave] = acc;
  __syncthreads();
  if (threadIdx.x == 0) part[blockIdx.x] = (red[0] + red[1]) + (red[2] + red[3]);
}

// Stage 2: one wave sums the 66 partials.
__global__ void final2(const float* __restrict__ part, float* __restrict__ out) {
  const int lane = threadIdx.x;
  float acc = part[lane];                       // 66 entries, lanes 0..63
  if (lane < 2) acc += part[lane + 64];
#pragma unroll
  for (int off = 32; off; off >>= 1) acc += __shfl_xor(acc, off);
  if (lane == 0) out[0] = acc;
}

extern "C" void kernel_launch(void* const* d_in, const int* in_sizes, int n_in,
                              void* d_out, int out_size, void* d_ws, size_t ws_size,
                              hipStream_t stream) {
  const float* outPts = (const float*)d_in[0];
  const float* tgtPts = (const float*)d_in[1];
  float* out = (float*)d_out;

  char* ws = (char*)d_ws;
  float4* pwA = (float4*)ws;                                  // 32768 * 16 B
  float4* pwB = (float4*)(ws + (size_t)NBATCH * NPTS * 16);   // 32768 * 16 B
  float*  f   = (float*)(ws + (size_t)2 * NBATCH * NPTS * 16);// 32768 floats
  float*  g   = f + NBATCH * NPTS;                            // 32768 floats
  float*  cham = g + NBATCH * NPTS;                           // 2048 floats
  float*  part = cham + 2048;                                 // 66 floats
  // total ws use: ~1.26 MB

  pack_pts<<<dim3(128), dim3(256), 0, stream>>>(outPts, tgtPts, pwA, pwB);

  const dim3 grid(NBATCH * BLOCKS_PER_BATCH);  // 1024 blocks x 256 threads
  const dim3 blk(THREADS);

  // iteration 1: f==0 (INIT), fuse both chamfer directions
  lse_pass<true,  true ><<<grid, blk, 0, stream>>>(pwA, pwB, nullptr, g, cham);
  lse_pass<false, true ><<<grid, blk, 0, stream>>>(pwB, pwA, g, f, cham + 1024);
  // iterations 2..10
  for (int t = 1; t < 10; ++t) {
    lse_pass<false, false><<<grid, blk, 0, stream>>>(pwA, pwB, f, g, nullptr);
    lse_pass<false, false><<<grid, blk, 0, stream>>>(pwB, pwA, g, f, nullptr);
  }

  // emd_loss = sum(f) + sum(g) (N==M), plus chamfer partials; contiguous from f.
  final1<<<dim3(66), dim3(256), 0, stream>>>((const float4*)f, part);
  final2<<<dim3(1), dim3(64), 0, stream>>>(part, out);
}

// Round 14
// 363.060 us; speedup vs baseline: 1.1509x; 1.0484x over previous
//
#include <hip/hip_runtime.h>
#include <math.h>

// Problem constants (B=16, N=M=2048, eps=0.05, 10 sinkhorn iters)
#define NPTS    2048
#define NBATCH  16
#define THREADS 256
#define BLOCKS_PER_BATCH 64     // 1024 blocks = 4/CU x 256 CU exactly
#define ROWS_PER_BLOCK   32
#define ROWS_PER_WAVE    8
#define IPAIRS  1024            // i handled as pairs (k, k+1024)

typedef __attribute__((ext_vector_type(2))) float f2;

static constexpr float KEPS_L  = 28.853900817779268f;   // log2(e)/eps
static constexpr float LOGMU_L = -11.0f;                 // log_mu*log2(e) = -log2(2048), exact
static constexpr float EPS_LN2 = 0.03465735902799727f;   // eps*ln(2)
static constexpr float INV_K2  = 1.2011331562368226e-3f; // 1/KEPS_L^2

// Pack both point clouds as K-scaled float4 {Kx,Ky,Kz,|Kp|^2}.
__global__ void pack_pts(const float* __restrict__ a, const float* __restrict__ b,
                         float4* __restrict__ pa, float4* __restrict__ pb) {
  int idx = blockIdx.x * blockDim.x + threadIdx.x;
  if (idx < NBATCH * NPTS) {
    float x = KEPS_L * a[3*idx], y = KEPS_L * a[3*idx+1], z = KEPS_L * a[3*idx+2];
    pa[idx] = make_float4(x, y, z, fmaf(x, x, fmaf(y, y, z*z)));
    float u = KEPS_L * b[3*idx], v = KEPS_L * b[3*idx+1], w = KEPS_L * b[3*idx+2];
    pb[idx] = make_float4(u, v, w, fmaf(u, u, fmaf(v, v, w*w)));
  }
}

// One half-iteration of log-domain Sinkhorn (exp2-domain, per-batch shift A).
// EMPIRICAL OPTIMUM (round 11, 363 us): SoA-f2 LDS over i-PAIRS (k, k+1024),
// q-side splats hoisted (loop-invariant), HW v_sqrt + v_exp2 in-chain,
// no min-occupancy launch bound (r10: forcing 4 w/SIMD at 64 VGPR caused
// 250 MB/dispatch scratch spills). Perturbations all tested and rejected:
// trans->VALU swaps (r5/r7/r13 regress), 2x ILP (r4 neutral), 2x occupancy
// (r9 neutral-negative), sort+prune (r12 regress). Per-pair cost
// (1 sqrt + 1 exp2 + 5 pk-VALU) is the formulation's minimum.
template<bool INIT, bool CHAMFER>
__global__ __launch_bounds__(THREADS)
void lse_pass(const float4* __restrict__ pR, const float4* __restrict__ pQ,
              const float* __restrict__ dualR, float* __restrict__ dualQ,
              float* __restrict__ chamPart) {
  __shared__ f2 sxx[IPAIRS];
  __shared__ f2 syy[IPAIRS];
  __shared__ f2 szz[IPAIRS];
  __shared__ f2 sww[IPAIRS];   // {-0.5|Kp|^2 lo, hi}
  __shared__ f2 swt[IPAIRS];   // {w lo, w hi}
  // total 40960 B exactly -> 4 blocks/CU; sxx doubles as reduce scratch.

  const int b    = blockIdx.x >> 6;        // batch
  const int blk  = blockIdx.x & 63;        // block within batch
  const int tid  = threadIdx.x;
  const int lane = tid & 63;
  const int wave = tid >> 6;

  const float4* __restrict__ px = pR + b * NPTS;
  float A;

  if constexpr (INIT) {
    // f == 0: a_i = LOGMU_L for all i -> A = LOGMU_L, w_i = 1
#pragma unroll
    for (int u = 0; u < 4; ++u) {
      int k = tid + u * THREADS;
      float4 a4 = px[k];
      float4 b4 = px[k + IPAIRS];
      sxx[k] = (f2){a4.x, b4.x};
      syy[k] = (f2){a4.y, b4.y};
      szz[k] = (f2){a4.z, b4.z};
      sww[k] = (f2){-0.5f * a4.w, -0.5f * b4.w};
      swt[k] = (f2){1.f, 1.f};
    }
    A = LOGMU_L;
    __syncthreads();
  } else {
    const float* __restrict__ fb = dualR + b * NPTS;
    float av[8];
    float lm = -3.4e38f;
#pragma unroll
    for (int u = 0; u < 8; ++u) {
      int k = tid + u * THREADS;
      float a = fmaf(fb[k], KEPS_L, LOGMU_L);
      av[u] = a;
      lm = fmaxf(lm, a);
    }
#pragma unroll
    for (int off = 32; off; off >>= 1) lm = fmaxf(lm, __shfl_xor(lm, off));
    float* scratch = (float*)sxx;          // sxx not yet staged -> usable
    if (lane == 0) scratch[wave] = lm;
    __syncthreads();
    A = fmaxf(fmaxf(scratch[0], scratch[1]), fmaxf(scratch[2], scratch[3]));
    __syncthreads();                       // done reading scratch before staging
#pragma unroll
    for (int u = 0; u < 4; ++u) {
      int k = tid + u * THREADS;           // 0..1023; partner k+1024 -> av[u+4]
      float4 a4 = px[k];
      float4 b4 = px[k + IPAIRS];
      sxx[k] = (f2){a4.x, b4.x};
      syy[k] = (f2){a4.y, b4.y};
      szz[k] = (f2){a4.z, b4.z};
      sww[k] = (f2){-0.5f * a4.w, -0.5f * b4.w};
      swt[k] = (f2){__builtin_amdgcn_exp2f(av[u] - A),
                    __builtin_amdgcn_exp2f(av[u + 4] - A)};
    }
    __syncthreads();
  }

  const float4* __restrict__ qa = pQ + b * NPTS;
  float* __restrict__ gout = dualQ + b * NPTS;
  const int j0 = blk * ROWS_PER_BLOCK + wave * ROWS_PER_WAVE;

  // Q-side splats hoisted out of the loop (loop-invariant f2 constants)
  f2 qxx[8], qyy[8], qzz[8], qww[8], s2[8], m2[8];
#pragma unroll
  for (int r = 0; r < ROWS_PER_WAVE; ++r) {
    float4 q = qa[j0 + r];
    qxx[r] = (f2){q.x, q.x};
    qyy[r] = (f2){q.y, q.y};
    qzz[r] = (f2){q.z, q.z};
    qww[r] = (f2){q.w, q.w};
    s2[r] = (f2){0.f, 0.f};
    if constexpr (CHAMFER) m2[r] = (f2){3.4e38f, 3.4e38f};
  }

  const f2 kM2 = (f2){-2.f, -2.f};

#pragma unroll 2
  for (int it = 0; it < IPAIRS / 64; ++it) {
    const int k = it * 64 + lane;
    const f2 pxx = sxx[k];
    const f2 pyy = syy[k];
    const f2 pzz = szz[k];
    const f2 pww = sww[k];
    const f2 wt  = swt[k];
#pragma unroll
    for (int r = 0; r < ROWS_PER_WAVE; ++r) {
      f2 t  = __builtin_elementwise_fma(pxx, qxx[r],
              __builtin_elementwise_fma(pyy, qyy[r],
              __builtin_elementwise_fma(pzz, qzz[r], pww)));
      f2 d2 = __builtin_elementwise_fma(kM2, t, qww[r]);   // = K^2*dist^2 > 0
      if constexpr (CHAMFER) m2[r] = __builtin_elementwise_min(m2[r], d2);
      f2 e;
      e.x = __builtin_amdgcn_exp2f(-__builtin_amdgcn_sqrtf(d2.x));
      e.y = __builtin_amdgcn_exp2f(-__builtin_amdgcn_sqrtf(d2.y));
      s2[r] = __builtin_elementwise_fma(e, wt, s2[r]);
    }
  }

  float s[ROWS_PER_WAVE], m[ROWS_PER_WAVE];
#pragma unroll
  for (int r = 0; r < ROWS_PER_WAVE; ++r) {
    s[r] = s2[r].x + s2[r].y;
    if constexpr (CHAMFER) m[r] = fminf(m2[r].x, m2[r].y);
  }

  // full-wave xor reductions (all lanes end with the result)
#pragma unroll
  for (int off = 32; off; off >>= 1) {
#pragma unroll
    for (int r = 0; r < ROWS_PER_WAVE; ++r) {
      s[r] += __shfl_xor(s[r], off);
      if constexpr (CHAMFER) m[r] = fminf(m[r], __shfl_xor(m[r], off));
    }
  }

  if (lane == 0) {
#pragma unroll
    for (int r = 0; r < ROWS_PER_WAVE; ++r)
      gout[j0 + r] = -EPS_LN2 * (A + __builtin_amdgcn_logf(fmaxf(s[r], 1e-37f)));
  }

  if constexpr (CHAMFER) {
    float chamAcc = 0.f;
#pragma unroll
    for (int r = 0; r < ROWS_PER_WAVE; ++r) chamAcc += m[r];
    chamAcc *= INV_K2;                      // back to unscaled d2
    __syncthreads();                        // everyone done with LDS arrays
    float* scratch = (float*)sxx;
    if (lane == 0) scratch[wave] = chamAcc;
    __syncthreads();
    if (tid == 0)
      chamPart[blockIdx.x] = (scratch[0] + scratch[1]) + (scratch[2] + scratch[3]);
  }
}

// Stage 1: 66 blocks x 256 threads, one float4 per thread (66*256*4 = 67584
// floats = f(32768) + g(32768) + cham(2048), contiguous). Deterministic.
__global__ void final1(const float4* __restrict__ base, float* __restrict__ part) {
  __shared__ float red[4];
  const int idx = blockIdx.x * 256 + threadIdx.x;
  float4 v = base[idx];
  float acc = (v.x + v.y) + (v.z + v.w);
#pragma unroll
  for (int off = 32; off; off >>= 1) acc += __shfl_xor(acc, off);
  const int lane = threadIdx.x & 63, wave = threadIdx.x >> 6;
  if (lane == 0) red[wave] = acc;
  __syncthreads();
  if (threadIdx.x == 0) part[blockIdx.x] = (red[0] + red[1]) + (red[2] + red[3]);
}

// Stage 2: one wave sums the 66 partials.
__global__ void final2(const float* __restrict__ part, float* __restrict__ out) {
  const int lane = threadIdx.x;
  float acc = part[lane];                       // 66 entries, lanes 0..63
  if (lane < 2) acc += part[lane + 64];
#pragma unroll
  for (int off = 32; off; off >>= 1) acc += __shfl_xor(acc, off);
  if (lane == 0) out[0] = acc;
}

extern "C" void kernel_launch(void* const* d_in, const int* in_sizes, int n_in,
                              void* d_out, int out_size, void* d_ws, size_t ws_size,
                              hipStream_t stream) {
  const float* outPts = (const float*)d_in[0];
  const float* tgtPts = (const float*)d_in[1];
  float* out = (float*)d_out;

  char* ws = (char*)d_ws;
  float4* pwA = (float4*)ws;                                  // 32768 * 16 B
  float4* pwB = (float4*)(ws + (size_t)NBATCH * NPTS * 16);   // 32768 * 16 B
  float*  f   = (float*)(ws + (size_t)2 * NBATCH * NPTS * 16);// 32768 floats
  float*  g   = f + NBATCH * NPTS;                            // 32768 floats
  float*  cham = g + NBATCH * NPTS;                           // 2048 floats
  float*  part = cham + 2048;                                 // 66 floats
  // total ws use: ~1.26 MB

  pack_pts<<<dim3(128), dim3(256), 0, stream>>>(outPts, tgtPts, pwA, pwB);

  const dim3 grid(NBATCH * BLOCKS_PER_BATCH);  // 1024 blocks x 256 threads
  const dim3 blk(THREADS);

  // iteration 1: f==0 (INIT), fuse both chamfer directions
  lse_pass<true,  true ><<<grid, blk, 0, stream>>>(pwA, pwB, nullptr, g, cham);
  lse_pass<false, true ><<<grid, blk, 0, stream>>>(pwB, pwA, g, f, cham + 1024);
  // iterations 2..10
  for (int t = 1; t < 10; ++t) {
    lse_pass<false, false><<<grid, blk, 0, stream>>>(pwA, pwB, f, g, nullptr);
    lse_pass<false, false><<<grid, blk, 0, stream>>>(pwB, pwA, g, f, nullptr);
  }

  // emd_loss = sum(f) + sum(g) (N==M), plus chamfer partials; contiguous from f.
  final1<<<dim3(66), dim3(256), 0, stream>>>((const float4*)f, part);
  final2<<<dim3(1), dim3(64), 0, stream>>>(part, out);
}